// Round 5
// baseline (405.394 us; speedup 1.0000x reference)
//
#include <hip/hip_runtime.h>
#include <hip/hip_bf16.h>
#include <math.h>

#define T_TOK 2048
#define HD 1024
#define ID 2048
#define NE 8

typedef __attribute__((ext_vector_type(8))) short s16x8;
typedef __attribute__((ext_vector_type(8))) unsigned short u16x8;
typedef __attribute__((ext_vector_type(4))) float f32x4;
typedef __attribute__((ext_vector_type(4))) unsigned short u16x4;

__device__ __forceinline__ unsigned short f2bf(float f) {
  union { float f; unsigned u; } v; v.f = f;
  unsigned r = v.u + 0x7FFFu + ((v.u >> 16) & 1u);   // RNE
  return (unsigned short)(r >> 16);
}

// 8 fp32 -> bf16x8 fragment; scalar casts fuse to v_cvt_pk_bf16_f32 (m240)
__device__ __forceinline__ s16x8 cvt8(float4 a, float4 b) {
  union { s16x8 v; __hip_bfloat16 h[8]; } u;
  u.h[0] = __float2bfloat16(a.x); u.h[1] = __float2bfloat16(a.y);
  u.h[2] = __float2bfloat16(a.z); u.h[3] = __float2bfloat16(a.w);
  u.h[4] = __float2bfloat16(b.x); u.h[5] = __float2bfloat16(b.y);
  u.h[6] = __float2bfloat16(b.z); u.h[7] = __float2bfloat16(b.w);
  return u.v;
}

#define GLOAD16(gsrc, ldst) \
  __builtin_amdgcn_global_load_lds((const __attribute__((address_space(1))) void*)(gsrc), \
                                   (__attribute__((address_space(3))) void*)(ldst), 16, 0, 0)

#define WAIT_BARRIER() do { \
  asm volatile("s_waitcnt vmcnt(0) lgkmcnt(0)" ::: "memory"); \
  __builtin_amdgcn_s_barrier(); } while (0)

// ---------------- router: one wave per token ----------------
__global__ void router_k(const float* __restrict__ x, const float* __restrict__ gate,
                         int* __restrict__ cnt, int* __restrict__ tok,
                         float* __restrict__ wt, int* __restrict__ inv) {
  int wid = threadIdx.x >> 6, lane = threadIdx.x & 63;
  int t = blockIdx.x * 4 + wid;
  const float* xr = x + (size_t)t * HD;
  float acc[NE];
#pragma unroll
  for (int e = 0; e < NE; e++) acc[e] = 0.f;
  for (int h = lane; h < HD; h += 64) {
    float xv = xr[h];
#pragma unroll
    for (int e = 0; e < NE; e++) acc[e] += xv * gate[e * HD + h];
  }
#pragma unroll
  for (int e = 0; e < NE; e++)
    for (int off = 32; off; off >>= 1) acc[e] += __shfl_xor(acc[e], off);
  int i0 = 0;
#pragma unroll
  for (int e = 1; e < NE; e++) if (acc[e] > acc[i0]) i0 = e;
  int i1 = (i0 == 0) ? 1 : 0;
#pragma unroll
  for (int e = 0; e < NE; e++) if (e != i0 && acc[e] > acc[i1]) i1 = e;
  float w0 = 1.f / (1.f + expf(acc[i1] - acc[i0]));
  float w1 = 1.f - w0;
  if (lane == 0) {
    int p0 = atomicAdd(&cnt[i0], 1);
    tok[i0 * T_TOK + p0] = t; wt[i0 * T_TOK + p0] = w0;
    inv[2 * t] = (i0 << 16) | p0;
    int p1 = atomicAdd(&cnt[i1], 1);
    tok[i1 * T_TOK + p1] = t; wt[i1 * T_TOK + p1] = w1;
    inv[2 * t + 1] = (i1 << 16) | p1;
  }
}

__global__ void prefix_k(const int* __restrict__ cnt, int* __restrict__ offs) {
  if (threadIdx.x == 0) {
    int s = 0;
    for (int e = 0; e < NE; e++) { offs[e] = s; s += cnt[e]; }
  }
}

// gather token rows (fp32 -> bf16), compacted by expert
__global__ void gather_k(const float* __restrict__ x, const int* __restrict__ cnt,
                         const int* __restrict__ offs, const int* __restrict__ tok,
                         unsigned short* __restrict__ Xg) {
  int e = blockIdx.x >> 11, slot = blockIdx.x & 2047;
  if (slot >= cnt[e]) return;
  int t = tok[e * T_TOK + slot];
  int row = offs[e] + slot;
  int c = threadIdx.x * 4;
  float4 f = *(const float4*)(x + (size_t)t * HD + c);
  u16x4 o; o.x = f2bf(f.x); o.y = f2bf(f.y); o.z = f2bf(f.z); o.w = f2bf(f.w);
  *(u16x4*)(Xg + (size_t)row * HD + c) = o;
}

// ---------------- grouped GEMM1: act = w * silu(Xg@w1^T) * (Xg@w3^T) ----------------
// BM=256 BN=64 BK=32, 512 thr (8 waves, 4x2), all staging via global_load_lds.
// A: bf16 [256][32]/buf, granule swz ^(row&3). B1/B2: fp32 [64][32]/buf, swz ^(row&7),
// converted to bf16 at fragment assembly. Expert->XCD pinned 1-D grid.
__global__ __launch_bounds__(512, 4) void gemm1_k(
    const unsigned short* __restrict__ Xg, const float* __restrict__ w1,
    const float* __restrict__ w3, const int* __restrict__ cnt,
    const int* __restrict__ offs, const float* __restrict__ wt,
    unsigned short* __restrict__ act) {
  int bid = blockIdx.x;
  int e = bid & 7;
  int r2 = bid >> 3;
  int nt = r2 & 31, mt = r2 >> 5;
  int count = cnt[e];
  if (mt * 256 >= count) return;
  int i0 = nt * 64;
  int rbase = offs[e] + mt * 256;
  const float* W1 = w1 + (size_t)e * ID * HD;
  const float* W3 = w3 + (size_t)e * ID * HD;

  __shared__ __align__(16) unsigned short Ab[2][256 * 32];  // 16KB/buf
  __shared__ __align__(16) float B1b[2][64 * 32];           // 8KB/buf
  __shared__ __align__(16) float B2b[2][64 * 32];

  int tid = threadIdx.x;
  int wid = tid >> 6, lane = tid & 63;
  int wr = wid >> 1, wc = wid & 1;          // 4x2 wave grid, wave tile 64x32
  int l15 = lane & 15, hi = lane >> 4;

  // A staging sources (2 chunks x 128 rows), pre-swizzled global granule
  const unsigned short* aS[2];
#pragma unroll
  for (int c = 0; c < 2; c++)
    aS[c] = Xg + (size_t)(rbase + c * 128 + wid * 16 + (lane >> 2)) * HD
               + (((lane & 3) ^ ((lane >> 2) & 3)) * 8);
  // B staging sources (64 rows x 8 fp32-granules)
  const float* b1S = W1 + (size_t)(i0 + wid * 8 + (lane >> 3)) * HD
                        + (((lane & 7) ^ ((lane >> 3) & 7)) * 4);
  const float* b2S = W3 + (size_t)(i0 + wid * 8 + (lane >> 3)) * HD
                        + (((lane & 7) ^ ((lane >> 3) & 7)) * 4);

  f32x4 accg[4][2], accu[4][2];
#pragma unroll
  for (int m = 0; m < 4; m++)
#pragma unroll
    for (int n = 0; n < 2; n++) {
      accg[m][n] = (f32x4){0.f, 0.f, 0.f, 0.f};
      accu[m][n] = (f32x4){0.f, 0.f, 0.f, 0.f};
    }

  // read-side swizzled offsets (lane-uniform across m/n)
  int aswz = (hi ^ (l15 & 3)) * 8;          // elem offset within A row
  int bg0 = ((hi * 2) ^ (l15 & 7)) * 4;     // f32 offsets within B row
  int bg1 = ((hi * 2 + 1) ^ (l15 & 7)) * 4;

#define G1_STAGE(buf, k0) do { \
    GLOAD16(aS[0] + (k0), &Ab[buf][wid * 512]); \
    GLOAD16(aS[1] + (k0), &Ab[buf][4096 + wid * 512]); \
    GLOAD16(b1S + (k0), &B1b[buf][wid * 256]); \
    GLOAD16(b2S + (k0), &B2b[buf][wid * 256]); } while (0)

  G1_STAGE(0, 0);
  WAIT_BARRIER();

  for (int t = 0; t < 32; ++t) {
    int cur = t & 1;
    if (t < 31) G1_STAGE(cur ^ 1, (t + 1) * 32);
    s16x8 a[4];
#pragma unroll
    for (int m = 0; m < 4; m++)
      a[m] = *(const s16x8*)&Ab[cur][(wr * 64 + m * 16 + l15) * 32 + aswz];
#pragma unroll
    for (int n = 0; n < 2; n++) {
      int rB = (wc * 32 + n * 16 + l15) * 32;
      float4 q0 = *(const float4*)&B1b[cur][rB + bg0];
      float4 q1 = *(const float4*)&B1b[cur][rB + bg1];
      s16x8 b1 = cvt8(q0, q1);
      float4 q2 = *(const float4*)&B2b[cur][rB + bg0];
      float4 q3 = *(const float4*)&B2b[cur][rB + bg1];
      s16x8 b2 = cvt8(q2, q3);
#pragma unroll
      for (int m = 0; m < 4; m++) {
        accg[m][n] = __builtin_amdgcn_mfma_f32_16x16x32_bf16(a[m], b1, accg[m][n], 0, 0, 0);
        accu[m][n] = __builtin_amdgcn_mfma_f32_16x16x32_bf16(a[m], b2, accu[m][n], 0, 0, 0);
      }
    }
    WAIT_BARRIER();
  }

  // epilogue: w * silu(g) * u -> bf16 act (C/D map: col=lane&15, row=(lane>>4)*4+reg)
#pragma unroll
  for (int m = 0; m < 4; m++)
#pragma unroll
    for (int r = 0; r < 4; r++) {
      int rl = mt * 256 + wr * 64 + m * 16 + hi * 4 + r;
      if (rl < count) {
        float w = wt[e * T_TOK + rl];
#pragma unroll
        for (int n = 0; n < 2; n++) {
          float g = accg[m][n][r], u = accu[m][n][r];
          float s = (g / (1.f + expf(-g))) * u * w;
          act[(size_t)(offs[e] + rl) * ID + i0 + wc * 32 + n * 16 + l15] =
              (unsigned short)__bfloat16_as_ushort(__float2bfloat16(s));
        }
      }
    }
#undef G1_STAGE
}

// ---------------- grouped GEMM2: ye = act @ w2^T ----------------
// BM=256 BN=64 BK=32, K=ID=2048, same structure, single B tensor.
__global__ __launch_bounds__(512, 4) void gemm2_k(
    const unsigned short* __restrict__ act, const float* __restrict__ w2,
    const int* __restrict__ cnt, const int* __restrict__ offs,
    float* __restrict__ ye) {
  int bid = blockIdx.x;
  int e = bid & 7;
  int r2 = bid >> 3;
  int nt = r2 & 15, mt = r2 >> 4;
  int count = cnt[e];
  if (mt * 256 >= count) return;
  int h0 = nt * 64;
  int rbase = offs[e] + mt * 256;
  const float* W2 = w2 + (size_t)e * HD * ID;   // [1024][2048]

  __shared__ __align__(16) unsigned short Ab[2][256 * 32];
  __shared__ __align__(16) float Bb[2][64 * 32];

  int tid = threadIdx.x;
  int wid = tid >> 6, lane = tid & 63;
  int wr = wid >> 1, wc = wid & 1;
  int l15 = lane & 15, hi = lane >> 4;

  const unsigned short* aS[2];
#pragma unroll
  for (int c = 0; c < 2; c++)
    aS[c] = act + (size_t)(rbase + c * 128 + wid * 16 + (lane >> 2)) * ID
                + (((lane & 3) ^ ((lane >> 2) & 3)) * 8);
  const float* bS = W2 + (size_t)(h0 + wid * 8 + (lane >> 3)) * ID
                       + (((lane & 7) ^ ((lane >> 3) & 7)) * 4);

  f32x4 acc[4][2];
#pragma unroll
  for (int m = 0; m < 4; m++)
#pragma unroll
    for (int n = 0; n < 2; n++) acc[m][n] = (f32x4){0.f, 0.f, 0.f, 0.f};

  int aswz = (hi ^ (l15 & 3)) * 8;
  int bg0 = ((hi * 2) ^ (l15 & 7)) * 4;
  int bg1 = ((hi * 2 + 1) ^ (l15 & 7)) * 4;

#define G2_STAGE(buf, k0) do { \
    GLOAD16(aS[0] + (k0), &Ab[buf][wid * 512]); \
    GLOAD16(aS[1] + (k0), &Ab[buf][4096 + wid * 512]); \
    GLOAD16(bS + (k0), &Bb[buf][wid * 256]); } while (0)

  G2_STAGE(0, 0);
  WAIT_BARRIER();

  for (int t = 0; t < 64; ++t) {
    int cur = t & 1;
    if (t < 63) G2_STAGE(cur ^ 1, (t + 1) * 32);
    s16x8 a[4];
#pragma unroll
    for (int m = 0; m < 4; m++)
      a[m] = *(const s16x8*)&Ab[cur][(wr * 64 + m * 16 + l15) * 32 + aswz];
#pragma unroll
    for (int n = 0; n < 2; n++) {
      int rB = (wc * 32 + n * 16 + l15) * 32;
      float4 q0 = *(const float4*)&Bb[cur][rB + bg0];
      float4 q1 = *(const float4*)&Bb[cur][rB + bg1];
      s16x8 b = cvt8(q0, q1);
#pragma unroll
      for (int m = 0; m < 4; m++)
        acc[m][n] = __builtin_amdgcn_mfma_f32_16x16x32_bf16(a[m], b, acc[m][n], 0, 0, 0);
    }
    WAIT_BARRIER();
  }

#pragma unroll
  for (int m = 0; m < 4; m++)
#pragma unroll
    for (int r = 0; r < 4; r++) {
      int slot = mt * 256 + wr * 64 + m * 16 + hi * 4 + r;
      if (slot < count) {
#pragma unroll
        for (int n = 0; n < 2; n++)
          ye[(size_t)(offs[e] + slot) * HD + h0 + wc * 32 + n * 16 + l15] = acc[m][n][r];
      }
    }
#undef G2_STAGE
}

// ---------------- combine: out[t] = ye[slot0] + ye[slot1] ----------------
__global__ void combine_k(const float* __restrict__ ye, const int* __restrict__ inv,
                          const int* __restrict__ offs, float* __restrict__ out) {
  int t = blockIdx.x;
  int c = threadIdx.x * 4;
  int v0 = inv[2 * t], v1 = inv[2 * t + 1];
  int r0 = offs[v0 >> 16] + (v0 & 0xFFFF);
  int r1 = offs[v1 >> 16] + (v1 & 0xFFFF);
  float4 a = *(const float4*)(ye + (size_t)r0 * HD + c);
  float4 b = *(const float4*)(ye + (size_t)r1 * HD + c);
  float4 o = {a.x + b.x, a.y + b.y, a.z + b.z, a.w + b.w};
  *(float4*)(out + (size_t)t * HD + c) = o;
}

extern "C" void kernel_launch(void* const* d_in, const int* in_sizes, int n_in,
                              void* d_out, int out_size, void* d_ws, size_t ws_size,
                              hipStream_t stream) {
  const float* x    = (const float*)d_in[0];
  const float* gate = (const float*)d_in[1];
  const float* w1   = (const float*)d_in[2];
  const float* w3   = (const float*)d_in[3];
  const float* w2   = (const float*)d_in[4];
  float* out = (float*)d_out;

  char* ws = (char*)d_ws;
  int* cnt  = (int*)(ws + 0);
  int* offs = (int*)(ws + 256);
  int* tok  = (int*)(ws + 512);                           // 64K
  float* wt = (float*)(ws + 66048);                       // 64K
  int* inv  = (int*)(ws + 131584);                        // 16K
  unsigned short* Xg  = (unsigned short*)(ws + 148480);   // 5120 x 1024 bf16 = 10.5M (pad rows: tail-tile overreads)
  unsigned short* act = (unsigned short*)(ws + 10634240); // 5120 x 2048 bf16 = 21.0M
  float* ye = (float*)(ws + 31605760);                    // 4224 x 1024 f32 = 17.3M -> ends ~48.9M

  hipMemsetAsync(cnt, 0, 256, stream);

  router_k<<<T_TOK / 4, 256, 0, stream>>>(x, gate, cnt, tok, wt, inv);
  prefix_k<<<1, 64, 0, stream>>>(cnt, offs);
  gather_k<<<NE * T_TOK, 256, 0, stream>>>(x, cnt, offs, tok, Xg);
  // 1-D grids, expert = bid & 7 -> expert->XCD pinning for L2 locality
  gemm1_k<<<NE * 32 * 4, 512, 0, stream>>>(Xg, w1, w3, cnt, offs, wt, act);
  gemm2_k<<<NE * 16 * 4, 512, 0, stream>>>(act, w2, cnt, offs, ye);
  combine_k<<<T_TOK, 256, 0, stream>>>(ye, inv, offs, out);
}